// Round 2
// baseline (1212.364 us; speedup 1.0000x reference)
//
#include <hip/hip_runtime.h>

// GCN graph classifier: 3x (GCNConv -> GraphNorm -> [residual] -> ReLU) -> mean-pool -> linear.
// Strategy: build CSR (by destination col) once per call, reuse for all 3 convs.
// Gather kernel: one 64-lane wave per node; lanes = 8 edge-slots x 8 feature-quads (float4).
// GraphNorm stats (sum, sumsq) fused into gather epilogue via atomics; one-pass var.
// Workspace requirement: ~48 MB.

#define NN 100000
#define NE 1600000
#define NG 1024
#define HD 32
#define EPSV 1e-5f

__global__ __launch_bounds__(256) void k_init(const int* __restrict__ batch,
                                              int* __restrict__ deg,
                                              float* __restrict__ cntf) {
    int v = blockIdx.x * 256 + threadIdx.x;
    if (v < NN) {
        deg[v] = 1;  // self loop
        atomicAdd(&cntf[batch[v]], 1.0f);
    }
}

__global__ __launch_bounds__(256) void k_count(const int* __restrict__ col,
                                               int* __restrict__ deg) {
    int e = blockIdx.x * 256 + threadIdx.x;
    if (e < NE) atomicAdd(&deg[col[e]], 1);
}

// Wave-level exclusive scan of deg -> start offsets; one global atomic per wave.
__global__ __launch_bounds__(256) void k_alloc(const int* __restrict__ deg,
                                               int* __restrict__ start,
                                               float* __restrict__ dinv,
                                               int* __restrict__ counter) {
    int v = blockIdx.x * 256 + threadIdx.x;
    int lane = threadIdx.x & 63;
    int d = (v < NN) ? deg[v] : 0;
    int incl = d;
    #pragma unroll
    for (int off = 1; off < 64; off <<= 1) {
        int n = __shfl_up(incl, off);
        if (lane >= off) incl += n;
    }
    int total = __shfl(incl, 63);
    int base = 0;
    if (lane == 63) base = atomicAdd(counter, total);
    base = __shfl(base, 63);
    if (v < NN) {
        start[v] = base + incl - d;
        dinv[v] = rsqrtf((float)d);   // deg >= 1 always (self loop)
    }
}

__global__ __launch_bounds__(256) void k_fill(const int* __restrict__ row,
                                              const int* __restrict__ col,
                                              const int* __restrict__ start,
                                              int* __restrict__ fill,
                                              int* __restrict__ csr_src) {
    int e = blockIdx.x * 256 + threadIdx.x;
    if (e >= NE + NN) return;
    int r, c;
    if (e < NE) { r = row[e]; c = col[e]; }
    else        { r = e - NE; c = r; }       // self loops
    int pos = start[c] + atomicAdd(&fill[c], 1);
    csr_src[pos] = r;
}

// hs[v][f] = dinv[v] * sum_k xin[v][k] * W[k][f]
template <int K>
__global__ __launch_bounds__(256) void k_premul(const float* __restrict__ xin,
                                                const float* __restrict__ W,
                                                const float* __restrict__ dinv,
                                                float* __restrict__ hs) {
    __shared__ float sW[K * HD];
    for (int i = threadIdx.x; i < K * HD; i += 256) sW[i] = W[i];
    __syncthreads();
    int t = blockIdx.x * 256 + threadIdx.x;
    int v = t >> 5, f = t & 31;
    if (v >= NN) return;
    const float* xv = xin + (size_t)v * K;
    float acc = 0.f;
    #pragma unroll
    for (int k = 0; k < K; k++) acc += xv[k] * sW[k * HD + f];
    hs[v * HD + f] = dinv[v] * acc;
}

// One wave per destination node: 8 edge-slots x 8 feature-quads (float4 per lane).
// out[v][f] = b[f] + dinv[v] * sum_{e in N(v)} hs[src][f]
// Fused GraphNorm stats: atomicAdd into per-(graph,feature) sum and sumsq.
__global__ __launch_bounds__(256) void k_gather(const float* __restrict__ hs,
                                                const int* __restrict__ csr_src,
                                                const int* __restrict__ start,
                                                const int* __restrict__ deg,
                                                const float* __restrict__ dinv,
                                                const float* __restrict__ bias,
                                                const int* __restrict__ batch,
                                                float* __restrict__ outb,
                                                float* __restrict__ gsum,
                                                float* __restrict__ gsq) {
    int wid = (blockIdx.x * 256 + threadIdx.x) >> 6;
    if (wid >= NN) return;
    int lane = threadIdx.x & 63;
    int q = lane & 7;      // feature quad: features q*4 .. q*4+3
    int es = lane >> 3;    // edge slot 0..7
    int s = start[wid], d = deg[wid];
    float4 acc = make_float4(0.f, 0.f, 0.f, 0.f);
    for (int i = es; i < d; i += 8) {
        int src = csr_src[s + i];
        const float4 h = *reinterpret_cast<const float4*>(hs + (size_t)src * HD + q * 4);
        acc.x += h.x; acc.y += h.y; acc.z += h.z; acc.w += h.w;
    }
    #pragma unroll
    for (int off = 8; off < 64; off <<= 1) {
        acc.x += __shfl_xor(acc.x, off);
        acc.y += __shfl_xor(acc.y, off);
        acc.z += __shfl_xor(acc.z, off);
        acc.w += __shfl_xor(acc.w, off);
    }
    if (es == 0) {
        float dv = dinv[wid];
        const float4 bq = *reinterpret_cast<const float4*>(bias + q * 4);
        float4 val;
        val.x = bq.x + dv * acc.x;
        val.y = bq.y + dv * acc.y;
        val.z = bq.z + dv * acc.z;
        val.w = bq.w + dv * acc.w;
        *reinterpret_cast<float4*>(outb + (size_t)wid * HD + q * 4) = val;
        int g = batch[wid];
        float* gs = gsum + g * HD + q * 4;
        float* gq = gsq  + g * HD + q * 4;
        atomicAdd(gs + 0, val.x);
        atomicAdd(gs + 1, val.y);
        atomicAdd(gs + 2, val.z);
        atomicAdd(gs + 3, val.w);
        atomicAdd(gq + 0, val.x * val.x);
        atomicAdd(gq + 1, val.y * val.y);
        atomicAdd(gq + 2, val.z * val.z);
        atomicAdd(gq + 3, val.w * val.w);
    }
}

// GraphNorm finalize + optional residual + ReLU + optional pooling atomics. float4 per thread.
template <bool RES, bool POOL>
__global__ __launch_bounds__(256) void k_norm(const float* __restrict__ o,
                                              const float* __restrict__ gsum,
                                              const float* __restrict__ gsq,
                                              const float* __restrict__ cntf,
                                              const int* __restrict__ batch,
                                              const float* __restrict__ gamma,
                                              const float* __restrict__ beta,
                                              const float* __restrict__ msc,
                                              const float* __restrict__ xprev,
                                              float* __restrict__ xout,
                                              float* __restrict__ pooled) {
    int t = blockIdx.x * 256 + threadIdx.x;
    int v = t >> 3, q = t & 7;
    if (v >= NN) return;
    int g = batch[v];
    float c = fmaxf(cntf[g], 1.f);
    float inv = 1.f / c;
    const float4 sm4 = *reinterpret_cast<const float4*>(gsum + g * HD + q * 4);
    const float4 sq4 = *reinterpret_cast<const float4*>(gsq  + g * HD + q * 4);
    const float4 ms4 = *reinterpret_cast<const float4*>(msc   + q * 4);
    const float4 ga4 = *reinterpret_cast<const float4*>(gamma + q * 4);
    const float4 be4 = *reinterpret_cast<const float4*>(beta  + q * 4);
    const float4 o4  = *reinterpret_cast<const float4*>(o + (size_t)v * HD + q * 4);
    float4 xp4 = make_float4(0.f, 0.f, 0.f, 0.f);
    if (RES) xp4 = *reinterpret_cast<const float4*>(xprev + (size_t)v * HD + q * 4);
    float4 y;
    {
        float m = sm4.x * inv, mq = sq4.x * inv, ms = ms4.x;
        float ctr = o4.x - m * ms;
        float var = mq - m * m * ms * (2.f - ms);   // E[(x-m*ms)^2]
        y.x = ga4.x * ctr * rsqrtf(var + EPSV) + be4.x;
    }
    {
        float m = sm4.y * inv, mq = sq4.y * inv, ms = ms4.y;
        float ctr = o4.y - m * ms;
        float var = mq - m * m * ms * (2.f - ms);
        y.y = ga4.y * ctr * rsqrtf(var + EPSV) + be4.y;
    }
    {
        float m = sm4.z * inv, mq = sq4.z * inv, ms = ms4.z;
        float ctr = o4.z - m * ms;
        float var = mq - m * m * ms * (2.f - ms);
        y.z = ga4.z * ctr * rsqrtf(var + EPSV) + be4.z;
    }
    {
        float m = sm4.w * inv, mq = sq4.w * inv, ms = ms4.w;
        float ctr = o4.w - m * ms;
        float var = mq - m * m * ms * (2.f - ms);
        y.w = ga4.w * ctr * rsqrtf(var + EPSV) + be4.w;
    }
    if (RES) { y.x += xp4.x; y.y += xp4.y; y.z += xp4.z; y.w += xp4.w; }
    y.x = fmaxf(y.x, 0.f); y.y = fmaxf(y.y, 0.f);
    y.z = fmaxf(y.z, 0.f); y.w = fmaxf(y.w, 0.f);
    *reinterpret_cast<float4*>(xout + (size_t)v * HD + q * 4) = y;
    if (POOL) {
        float* p = pooled + g * HD + q * 4;
        atomicAdd(p + 0, y.x);
        atomicAdd(p + 1, y.y);
        atomicAdd(p + 2, y.z);
        atomicAdd(p + 3, y.w);
    }
}

__global__ __launch_bounds__(256) void k_final(const float* __restrict__ pooled,
                                               const float* __restrict__ cntf,
                                               const float* __restrict__ Wl,
                                               const float* __restrict__ bl,
                                               float* __restrict__ out) {
    int g = blockIdx.x * 256 + threadIdx.x;
    if (g >= NG) return;
    float inv = 1.f / fmaxf(cntf[g], 1.f);
    float a0 = bl[0], a1 = bl[1], a2 = bl[2];
    #pragma unroll
    for (int f = 0; f < HD; f++) {
        float p = pooled[g * HD + f] * inv;
        a0 += p * Wl[f * 3 + 0];
        a1 += p * Wl[f * 3 + 1];
        a2 += p * Wl[f * 3 + 2];
    }
    out[g * 3 + 0] = a0;
    out[g * 3 + 1] = a1;
    out[g * 3 + 2] = a2;
}

extern "C" void kernel_launch(void* const* d_in, const int* in_sizes, int n_in,
                              void* d_out, int out_size, void* d_ws, size_t ws_size,
                              hipStream_t stream) {
    const float* x     = (const float*)d_in[0];
    const int*   ei    = (const int*)d_in[1];     // [2, NE]
    const int*   batch = (const int*)d_in[2];
    const float* W1 = (const float*)d_in[3];
    const float* b1 = (const float*)d_in[4];
    const float* W2 = (const float*)d_in[5];
    const float* b2 = (const float*)d_in[6];
    const float* W3 = (const float*)d_in[7];
    const float* b3 = (const float*)d_in[8];
    const float* g1 = (const float*)d_in[9];
    const float* be1 = (const float*)d_in[10];
    const float* ms1 = (const float*)d_in[11];
    const float* g2 = (const float*)d_in[12];
    const float* be2 = (const float*)d_in[13];
    const float* ms2 = (const float*)d_in[14];
    const float* g3 = (const float*)d_in[15];
    const float* be3 = (const float*)d_in[16];
    const float* ms3 = (const float*)d_in[17];
    const float* Wl = (const float*)d_in[18];
    const float* bl = (const float*)d_in[19];
    float* out = (float*)d_out;

    const int* row = ei;
    const int* col = ei + NE;

    // ---- workspace layout (all 16B aligned) ----
    char* ws = (char*)d_ws;
    size_t off = 0;
    // zeroed region:
    int*   fill    = (int*)(ws + off);  off += (size_t)NN * 4;
    int*   counter = (int*)(ws + off);  off += 16;
    float* gsum1   = (float*)(ws + off); off += (size_t)NG * HD * 4;
    float* gsq1    = (float*)(ws + off); off += (size_t)NG * HD * 4;
    float* gsum2   = (float*)(ws + off); off += (size_t)NG * HD * 4;
    float* gsq2    = (float*)(ws + off); off += (size_t)NG * HD * 4;
    float* gsum3   = (float*)(ws + off); off += (size_t)NG * HD * 4;
    float* gsq3    = (float*)(ws + off); off += (size_t)NG * HD * 4;
    float* pooled  = (float*)(ws + off); off += (size_t)NG * HD * 4;
    float* cntf    = (float*)(ws + off); off += (size_t)NG * 4;
    size_t zero_bytes = off;
    // non-zeroed region:
    int*   deg     = (int*)(ws + off);   off += (size_t)NN * 4;
    int*   start   = (int*)(ws + off);   off += (size_t)NN * 4;
    float* dinv    = (float*)(ws + off); off += (size_t)NN * 4;
    int*   csr_src = (int*)(ws + off);   off += (size_t)(NE + NN) * 4;
    float* bufH    = (float*)(ws + off); off += (size_t)NN * HD * 4;
    float* bufO    = (float*)(ws + off); off += (size_t)NN * HD * 4;
    float* bufX    = (float*)(ws + off); off += (size_t)NN * HD * 4;
    (void)ws_size; (void)in_sizes; (void)n_in; (void)out_size;

    hipMemsetAsync(ws, 0, zero_bytes, stream);

    const int nb_n   = (NN + 255) / 256;             // 391
    const int nb_e   = (NE + 255) / 256;             // 6250
    const int nb_et  = (NE + NN + 255) / 256;        // 6641
    const int nb_nf  = (NN * HD + 255) / 256;        // 12500
    const int nb_nq  = (NN * 8 + 255) / 256;         // 3125
    const int nb_gw  = (NN * 64 + 255) / 256;        // 25000

    // ---- CSR build (once, reused by all 3 convs) ----
    k_init <<<nb_n, 256, 0, stream>>>(batch, deg, cntf);
    k_count<<<nb_e, 256, 0, stream>>>(col, deg);
    k_alloc<<<nb_n, 256, 0, stream>>>(deg, start, dinv, counter);
    k_fill <<<nb_et, 256, 0, stream>>>(row, col, start, fill, csr_src);

    // ---- layer 1 ----
    k_premul<3><<<nb_nf, 256, 0, stream>>>(x, W1, dinv, bufH);
    k_gather<<<nb_gw, 256, 0, stream>>>(bufH, csr_src, start, deg, dinv, b1, batch,
                                        bufO, gsum1, gsq1);
    k_norm<false, false><<<nb_nq, 256, 0, stream>>>(bufO, gsum1, gsq1, cntf, batch,
                                                    g1, be1, ms1, nullptr, bufX, nullptr);

    // ---- layer 2 ----
    k_premul<HD><<<nb_nf, 256, 0, stream>>>(bufX, W2, dinv, bufH);
    k_gather<<<nb_gw, 256, 0, stream>>>(bufH, csr_src, start, deg, dinv, b2, batch,
                                        bufO, gsum2, gsq2);
    k_norm<true, false><<<nb_nq, 256, 0, stream>>>(bufO, gsum2, gsq2, cntf, batch,
                                                   g2, be2, ms2, bufX, bufX, nullptr);

    // ---- layer 3 (pooling fused) ----
    k_premul<HD><<<nb_nf, 256, 0, stream>>>(bufX, W3, dinv, bufH);
    k_gather<<<nb_gw, 256, 0, stream>>>(bufH, csr_src, start, deg, dinv, b3, batch,
                                        bufO, gsum3, gsq3);
    k_norm<true, true><<<nb_nq, 256, 0, stream>>>(bufO, gsum3, gsq3, cntf, batch,
                                                  g3, be3, ms3, bufX, bufX, pooled);

    // ---- readout ----
    k_final<<<(NG + 255) / 256, 256, 0, stream>>>(pooled, cntf, Wl, bl, out);
}

// Round 4
// 476.072 us; speedup vs baseline: 2.5466x; 2.5466x over previous
//
#include <hip/hip_runtime.h>
#include <hip/hip_fp16.h>

// GCN graph classifier: 3x (GCNConv -> GraphNorm -> [residual] -> ReLU) -> mean-pool -> linear.
// CSR built once (by destination), reused by all 3 convs.
// hs staged in fp16 (64 B rows: half the gather fetch, 2x better L2 residency).
// GraphNorm stats+normalize+pool fused into one block-per-graph kernel (batch is sorted,
// so each graph is a contiguous node range) -- no atomics in the hot path.
// Gather wave: 16 edge-slots x 4 feature-quads (16 B fp16 per lane), fp32 accumulate.

#define NN 100000
#define NE 1600000
#define NG 1024
#define HD 32
#define EPSV 1e-5f

// Graph boundary offsets from sorted batch: gstart[g] = first node of graph g; gstart[NG] = NN.
__global__ __launch_bounds__(256) void k_bound(const int* __restrict__ batch,
                                               int* __restrict__ gstart) {
    int v = blockIdx.x * 256 + threadIdx.x;
    if (v >= NN) return;
    int b = batch[v];
    int bp = (v > 0) ? batch[v - 1] : -1;
    for (int g = bp + 1; g <= b; g++) gstart[g] = v;
    if (v == NN - 1)
        for (int g = b + 1; g <= NG; g++) gstart[g] = NN;
}

__global__ __launch_bounds__(256) void k_count(const int* __restrict__ col,
                                               int* __restrict__ deg) {
    int e = blockIdx.x * 256 + threadIdx.x;
    if (e < NE) atomicAdd(&deg[col[e]], 1);
}

// deg[] holds edge-count only (zeroed); total slots per node = deg+1 (self loop).
// Wave-level exclusive scan -> start offsets; one global atomic per wave.
__global__ __launch_bounds__(256) void k_alloc(const int* __restrict__ deg,
                                               int* __restrict__ start,
                                               float* __restrict__ dinv,
                                               int* __restrict__ counter) {
    int v = blockIdx.x * 256 + threadIdx.x;
    int lane = threadIdx.x & 63;
    int d = (v < NN) ? (deg[v] + 1) : 0;
    int incl = d;
    #pragma unroll
    for (int off = 1; off < 64; off <<= 1) {
        int n = __shfl_up(incl, off);
        if (lane >= off) incl += n;
    }
    int total = __shfl(incl, 63);
    int base = 0;
    if (lane == 63) base = atomicAdd(counter, total);
    base = __shfl(base, 63);
    if (v < NN) {
        start[v] = base + incl - d;
        dinv[v] = rsqrtf((float)d);
    }
}

__global__ __launch_bounds__(256) void k_fill(const int* __restrict__ row,
                                              const int* __restrict__ col,
                                              const int* __restrict__ start,
                                              int* __restrict__ fill,
                                              int* __restrict__ csr_src) {
    int e = blockIdx.x * 256 + threadIdx.x;
    if (e >= NE + NN) return;
    int r, c;
    if (e < NE) { r = row[e]; c = col[e]; }
    else        { r = e - NE; c = r; }       // self loops
    int pos = start[c] + atomicAdd(&fill[c], 1);
    csr_src[pos] = r;
}

// hs[v][f] = (fp16) dinv[v] * sum_k xin[v][k] * W[k][f]; thread per (node, feature-octet).
template <int K>
__global__ __launch_bounds__(256) void k_premul(const float* __restrict__ xin,
                                                const float* __restrict__ W,
                                                const float* __restrict__ dinv,
                                                __half* __restrict__ hs) {
    __shared__ float sW[K * HD];
    for (int i = threadIdx.x; i < K * HD; i += 256) sW[i] = W[i];
    __syncthreads();
    int t = blockIdx.x * 256 + threadIdx.x;
    int v = t >> 2, o = t & 3;
    if (v >= NN) return;
    const float* xv = xin + (size_t)v * K;
    float acc[8] = {0.f, 0.f, 0.f, 0.f, 0.f, 0.f, 0.f, 0.f};
    #pragma unroll
    for (int k = 0; k < K; k++) {
        float xk = xv[k];
        #pragma unroll
        for (int j = 0; j < 8; j++) acc[j] += xk * sW[k * HD + o * 8 + j];
    }
    float dv = dinv[v];
    __half2 h[4];
    #pragma unroll
    for (int j = 0; j < 4; j++)
        h[j] = __floats2half2_rn(dv * acc[2 * j], dv * acc[2 * j + 1]);
    *reinterpret_cast<float4*>(hs + (size_t)v * HD + o * 8) = *reinterpret_cast<float4*>(h);
}

// One wave per destination node: 16 edge-slots x 4 feature-quads (16 B of fp16 per lane).
// out[v][f] = b[f] + dinv[v] * sum_{e in N(v)} hs[src][f]; fp32 accumulate.
__global__ __launch_bounds__(256) void k_gather(const __half* __restrict__ hs,
                                                const int* __restrict__ csr_src,
                                                const int* __restrict__ start,
                                                const int* __restrict__ deg,
                                                const float* __restrict__ dinv,
                                                const float* __restrict__ bias,
                                                float* __restrict__ outb) {
    int wid = (blockIdx.x * 256 + threadIdx.x) >> 6;
    if (wid >= NN) return;
    int lane = threadIdx.x & 63;
    int q = lane & 3;      // feature quad: halves q*8 .. q*8+7
    int es = lane >> 2;    // edge slot 0..15
    int s = start[wid], d = deg[wid] + 1;
    float acc[8] = {0.f, 0.f, 0.f, 0.f, 0.f, 0.f, 0.f, 0.f};
    for (int i = es; i < d; i += 16) {
        int src = csr_src[s + i];
        float4 raw = *reinterpret_cast<const float4*>(hs + (size_t)src * HD + q * 8);
        const __half2* hp = reinterpret_cast<const __half2*>(&raw);
        #pragma unroll
        for (int j = 0; j < 4; j++) {
            float2 f2 = __half22float2(hp[j]);
            acc[2 * j]     += f2.x;
            acc[2 * j + 1] += f2.y;
        }
    }
    #pragma unroll
    for (int off = 4; off < 64; off <<= 1) {
        #pragma unroll
        for (int j = 0; j < 8; j++) acc[j] += __shfl_xor(acc[j], off);
    }
    if (es == 0) {
        float dv = dinv[wid];
        float4 w0, w1;
        w0.x = bias[q * 8 + 0] + dv * acc[0];
        w0.y = bias[q * 8 + 1] + dv * acc[1];
        w0.z = bias[q * 8 + 2] + dv * acc[2];
        w0.w = bias[q * 8 + 3] + dv * acc[3];
        w1.x = bias[q * 8 + 4] + dv * acc[4];
        w1.y = bias[q * 8 + 5] + dv * acc[5];
        w1.z = bias[q * 8 + 6] + dv * acc[6];
        w1.w = bias[q * 8 + 7] + dv * acc[7];
        float* op = outb + (size_t)wid * HD + q * 8;
        *reinterpret_cast<float4*>(op)     = w0;
        *reinterpret_cast<float4*>(op + 4) = w1;
    }
}

// Fused GraphNorm (stats + normalize) + optional residual + ReLU + optional mean-pool+linear.
// One block per graph (batch sorted => contiguous node range). Phase-2 re-reads of o hit L1
// (~12 KB per graph). y = A*x + B with A = gamma*rsqrt(var+eps), B = beta - A*m*ms.
template <bool RES, bool POOL>
__global__ __launch_bounds__(256) void k_gnorm(const float* __restrict__ o,
                                               const int* __restrict__ gstart,
                                               const float* __restrict__ gamma,
                                               const float* __restrict__ beta,
                                               const float* __restrict__ msc,
                                               const float* __restrict__ xprev,
                                               float* __restrict__ xout,
                                               const float* __restrict__ Wl,
                                               const float* __restrict__ bl,
                                               float* __restrict__ outf) {
    int g = blockIdx.x;
    int s = gstart[g], e = gstart[g + 1];
    int f = threadIdx.x & 31, nl = threadIdx.x >> 5;   // 8 node-lanes x 32 features
    float as = 0.f, aq = 0.f;
    for (int v = s + nl; v < e; v += 8) {
        float xv = o[(size_t)v * HD + f];
        as += xv;
        aq += xv * xv;
    }
    __shared__ float ls[256], lq[256];
    __shared__ float sA[HD], sB[HD];
    ls[threadIdx.x] = as;
    lq[threadIdx.x] = aq;
    __syncthreads();
    if (threadIdx.x < HD) {
        float ss = 0.f, qq = 0.f;
        #pragma unroll
        for (int k = 0; k < 8; k++) { ss += ls[k * 32 + f]; qq += lq[k * 32 + f]; }
        float inv = 1.f / fmaxf((float)(e - s), 1.f);
        float m = ss * inv, mq = qq * inv, ms = msc[f];
        // var = E[(x - m*ms)^2] = E[x^2] - m^2 * ms * (2 - ms)
        float var = mq - m * m * ms * (2.f - ms);
        float A = gamma[f] * rsqrtf(var + EPSV);
        sA[f] = A;
        sB[f] = beta[f] - A * m * ms;
    }
    __syncthreads();
    float A = sA[f], B = sB[f];
    float pool = 0.f;
    for (int v = s + nl; v < e; v += 8) {
        float xv = o[(size_t)v * HD + f];
        float y = A * xv + B;
        if (RES) y += xprev[(size_t)v * HD + f];
        y = fmaxf(y, 0.f);
        xout[(size_t)v * HD + f] = y;
        if (POOL) pool += y;
    }
    if (POOL) {
        __syncthreads();
        ls[threadIdx.x] = pool;
        __syncthreads();
        if (threadIdx.x < HD) {
            float ss = 0.f;
            #pragma unroll
            for (int k = 0; k < 8; k++) ss += ls[k * 32 + f];
            lq[f] = ss / fmaxf((float)(e - s), 1.f);   // reuse lq: per-feature graph mean
        }
        __syncthreads();
        if (threadIdx.x < 3) {
            float acc = bl[threadIdx.x];
            #pragma unroll
            for (int f2 = 0; f2 < HD; f2++) acc += lq[f2] * Wl[f2 * 3 + threadIdx.x];
            outf[g * 3 + threadIdx.x] = acc;
        }
    }
}

extern "C" void kernel_launch(void* const* d_in, const int* in_sizes, int n_in,
                              void* d_out, int out_size, void* d_ws, size_t ws_size,
                              hipStream_t stream) {
    const float* x     = (const float*)d_in[0];
    const int*   ei    = (const int*)d_in[1];     // [2, NE]
    const int*   batch = (const int*)d_in[2];
    const float* W1 = (const float*)d_in[3];
    const float* b1 = (const float*)d_in[4];
    const float* W2 = (const float*)d_in[5];
    const float* b2 = (const float*)d_in[6];
    const float* W3 = (const float*)d_in[7];
    const float* b3 = (const float*)d_in[8];
    const float* g1 = (const float*)d_in[9];
    const float* be1 = (const float*)d_in[10];
    const float* ms1 = (const float*)d_in[11];
    const float* g2 = (const float*)d_in[12];
    const float* be2 = (const float*)d_in[13];
    const float* ms2 = (const float*)d_in[14];
    const float* g3 = (const float*)d_in[15];
    const float* be3 = (const float*)d_in[16];
    const float* ms3 = (const float*)d_in[17];
    const float* Wl = (const float*)d_in[18];
    const float* bl = (const float*)d_in[19];
    float* out = (float*)d_out;

    const int* row = ei;
    const int* col = ei + NE;

    // ---- workspace layout (16B aligned) ----
    char* ws = (char*)d_ws;
    size_t off = 0;
    // zeroed region:
    int*   fill    = (int*)(ws + off);   off += (size_t)NN * 4;
    int*   deg     = (int*)(ws + off);   off += (size_t)NN * 4;
    int*   counter = (int*)(ws + off);   off += 16;
    size_t zero_bytes = off;
    // non-zeroed region:
    int*   start   = (int*)(ws + off);   off += (size_t)NN * 4;
    float* dinv    = (float*)(ws + off); off += (size_t)NN * 4;
    int*   gstart  = (int*)(ws + off);   off += (size_t)(NG + 4) * 4;
    int*   csr_src = (int*)(ws + off);   off += (size_t)(NE + NN) * 4;
    __half* bufH   = (__half*)(ws + off); off += (size_t)NN * HD * 2;
    float* bufO    = (float*)(ws + off); off += (size_t)NN * HD * 4;
    float* bufX    = (float*)(ws + off); off += (size_t)NN * HD * 4;
    (void)ws_size; (void)in_sizes; (void)n_in; (void)out_size;

    hipMemsetAsync(ws, 0, zero_bytes, stream);

    const int nb_n   = (NN + 255) / 256;             // 391
    const int nb_e   = (NE + 255) / 256;             // 6250
    const int nb_et  = (NE + NN + 255) / 256;        // 6641
    const int nb_no  = (NN * 4 + 255) / 256;         // 1563  (node-octet threads)
    const int nb_gw  = (NN * 64 + 255) / 256;        // 25000 (wave per node)

    // ---- CSR build (once, reused by all 3 convs) ----
    k_bound<<<nb_n, 256, 0, stream>>>(batch, gstart);
    k_count<<<nb_e, 256, 0, stream>>>(col, deg);
    k_alloc<<<nb_n, 256, 0, stream>>>(deg, start, dinv, counter);
    k_fill <<<nb_et, 256, 0, stream>>>(row, col, start, fill, csr_src);

    // ---- layer 1 ----
    k_premul<3><<<nb_no, 256, 0, stream>>>(x, W1, dinv, bufH);
    k_gather<<<nb_gw, 256, 0, stream>>>(bufH, csr_src, start, deg, dinv, b1, bufO);
    k_gnorm<false, false><<<NG, 256, 0, stream>>>(bufO, gstart, g1, be1, ms1,
                                                  nullptr, bufX, nullptr, nullptr, nullptr);

    // ---- layer 2 ----
    k_premul<HD><<<nb_no, 256, 0, stream>>>(bufX, W2, dinv, bufH);
    k_gather<<<nb_gw, 256, 0, stream>>>(bufH, csr_src, start, deg, dinv, b2, bufO);
    k_gnorm<true, false><<<NG, 256, 0, stream>>>(bufO, gstart, g2, be2, ms2,
                                                 bufX, bufX, nullptr, nullptr, nullptr);

    // ---- layer 3 (pool + linear fused) ----
    k_premul<HD><<<nb_no, 256, 0, stream>>>(bufX, W3, dinv, bufH);
    k_gather<<<nb_gw, 256, 0, stream>>>(bufH, csr_src, start, deg, dinv, b3, bufO);
    k_gnorm<true, true><<<NG, 256, 0, stream>>>(bufO, gstart, g3, be3, ms3,
                                                bufX, bufX, Wl, bl, out);
}

// Round 6
// 431.092 us; speedup vs baseline: 2.8123x; 1.1043x over previous
//
#include <hip/hip_runtime.h>
#include <hip/hip_fp16.h>

// GCN graph classifier: 3x (GCNConv -> GraphNorm -> [residual] -> ReLU) -> mean-pool -> linear.
// CSR built once (by destination), reused by all 3 convs.
// hs staged in fp16 (64 B rows). GraphNorm fused block-per-graph (sorted batch).
// k_fill: 4 range-filtered passes, persistent blocks with fixed edge chunks ->
//   scatter writes + atomics confined to ~1.7 MB / 100 KB L2-resident regions per pass.
// k_gather: 16 edge-slots x 4 feature-quads, 2-deep software-pipelined row loads.

#define NN 100000
#define NE 1600000
#define NG 1024
#define HD 32
#define EPSV 1e-5f

#define FILL_PASSES 4
#define FILL_BLOCKS 2048
#define NPP ((NN + FILL_PASSES - 1) / FILL_PASSES)   // 25000 dests per pass

// Graph boundary offsets from sorted batch: gstart[g] = first node of graph g; gstart[NG] = NN.
__global__ __launch_bounds__(256) void k_bound(const int* __restrict__ batch,
                                               int* __restrict__ gstart) {
    int v = blockIdx.x * 256 + threadIdx.x;
    if (v >= NN) return;
    int b = batch[v];
    int bp = (v > 0) ? batch[v - 1] : -1;
    for (int g = bp + 1; g <= b; g++) gstart[g] = v;
    if (v == NN - 1)
        for (int g = b + 1; g <= NG; g++) gstart[g] = NN;
}

__global__ __launch_bounds__(256) void k_count(const int* __restrict__ col,
                                               int* __restrict__ deg) {
    int e = blockIdx.x * 256 + threadIdx.x;
    if (e < NE) atomicAdd(&deg[col[e]], 1);
}

// deg[] holds edge-count only (zeroed); total slots per node = deg+1 (self loop).
// Wave-level exclusive scan -> start offsets; one global atomic per wave.
__global__ __launch_bounds__(256) void k_alloc(const int* __restrict__ deg,
                                               int* __restrict__ start,
                                               float* __restrict__ dinv,
                                               int* __restrict__ counter) {
    int v = blockIdx.x * 256 + threadIdx.x;
    int lane = threadIdx.x & 63;
    int d = (v < NN) ? (deg[v] + 1) : 0;
    int incl = d;
    #pragma unroll
    for (int off = 1; off < 64; off <<= 1) {
        int n = __shfl_up(incl, off);
        if (lane >= off) incl += n;
    }
    int total = __shfl(incl, 63);
    int base = 0;
    if (lane == 63) base = atomicAdd(counter, total);
    base = __shfl(base, 63);
    if (v < NN) {
        start[v] = base + incl - d;
        dinv[v] = rsqrtf((float)d);
    }
}

// 4-pass range-filtered CSR fill. Persistent blocks: each owns a fixed contiguous edge
// chunk (L1/L2-resident across passes); pass p touches only dests [p*NPP,(p+1)*NPP) so
// the fill[] atomic region (100 KB) and csr_src write region (~1.7 MB) stay L2-resident.
__global__ __launch_bounds__(256) void k_fill(const int* __restrict__ row,
                                              const int* __restrict__ col,
                                              const int* __restrict__ start,
                                              int* __restrict__ fill,
                                              int* __restrict__ csr_src) {
    const int total = NE + NN;
    const int chunk = (total + FILL_BLOCKS - 1) / FILL_BLOCKS;
    int c0 = blockIdx.x * chunk;
    int c1 = min(c0 + chunk, total);
    for (int pass = 0; pass < FILL_PASSES; pass++) {
        int lo = pass * NPP;
        int hi = lo + NPP;
        for (int e = c0 + threadIdx.x; e < c1; e += 256) {
            int r, c;
            if (e < NE) { r = row[e]; c = col[e]; }
            else        { r = e - NE; c = r; }       // self loops
            if (c >= lo && c < hi) {
                int pos = start[c] + atomicAdd(&fill[c], 1);
                csr_src[pos] = r;
            }
        }
    }
}

// hs[v][f] = (fp16) dinv[v] * sum_k xin[v][k] * W[k][f]; thread per (node, feature-octet).
template <int K>
__global__ __launch_bounds__(256) void k_premul(const float* __restrict__ xin,
                                                const float* __restrict__ W,
                                                const float* __restrict__ dinv,
                                                __half* __restrict__ hs) {
    __shared__ float sW[K * HD];
    for (int i = threadIdx.x; i < K * HD; i += 256) sW[i] = W[i];
    __syncthreads();
    int t = blockIdx.x * 256 + threadIdx.x;
    int v = t >> 2, o = t & 3;
    if (v >= NN) return;
    const float* xv = xin + (size_t)v * K;
    float acc[8] = {0.f, 0.f, 0.f, 0.f, 0.f, 0.f, 0.f, 0.f};
    #pragma unroll
    for (int k = 0; k < K; k++) {
        float xk = xv[k];
        #pragma unroll
        for (int j = 0; j < 8; j++) acc[j] += xk * sW[k * HD + o * 8 + j];
    }
    float dv = dinv[v];
    __half2 h[4];
    #pragma unroll
    for (int j = 0; j < 4; j++)
        h[j] = __floats2half2_rn(dv * acc[2 * j], dv * acc[2 * j + 1]);
    *reinterpret_cast<float4*>(hs + (size_t)v * HD + o * 8) = *reinterpret_cast<float4*>(h);
}

// One wave per destination node: 16 edge-slots x 4 feature-quads (16 B fp16 per lane).
// 2-deep software pipeline: both typical iterations' loads issued before consumption
// (avg deg+1 ~ 17 -> exactly 2 iterations for most waves). fp32 accumulate.
__global__ __launch_bounds__(256) void k_gather(const __half* __restrict__ hs,
                                                const int* __restrict__ csr_src,
                                                const int* __restrict__ start,
                                                const int* __restrict__ deg,
                                                const float* __restrict__ dinv,
                                                const float* __restrict__ bias,
                                                float* __restrict__ outb) {
    int wid = (blockIdx.x * 256 + threadIdx.x) >> 6;
    if (wid >= NN) return;
    int lane = threadIdx.x & 63;
    int q = lane & 3;      // feature quad: halves q*8 .. q*8+7
    int es = lane >> 2;    // edge slot 0..15
    int s = start[wid], d = deg[wid] + 1;
    float acc[8] = {0.f, 0.f, 0.f, 0.f, 0.f, 0.f, 0.f, 0.f};

    bool a0 = (es < d);
    bool a1 = (es + 16 < d);
    int src0 = a0 ? csr_src[s + es] : 0;
    int src1 = a1 ? csr_src[s + es + 16] : 0;
    float4 raw0 = *reinterpret_cast<const float4*>(hs + (size_t)src0 * HD + q * 8);
    float4 raw1 = *reinterpret_cast<const float4*>(hs + (size_t)src1 * HD + q * 8);
    float m0 = a0 ? 1.f : 0.f;
    float m1 = a1 ? 1.f : 0.f;
    {
        const __half2* hp = reinterpret_cast<const __half2*>(&raw0);
        #pragma unroll
        for (int j = 0; j < 4; j++) {
            float2 f2 = __half22float2(hp[j]);
            acc[2 * j]     += m0 * f2.x;
            acc[2 * j + 1] += m0 * f2.y;
        }
    }
    {
        const __half2* hp = reinterpret_cast<const __half2*>(&raw1);
        #pragma unroll
        for (int j = 0; j < 4; j++) {
            float2 f2 = __half22float2(hp[j]);
            acc[2 * j]     += m1 * f2.x;
            acc[2 * j + 1] += m1 * f2.y;
        }
    }
    // rare tail (deg+1 > 32): Poisson(16) tail, ~0.02% of nodes
    for (int i = es + 32; i < d; i += 16) {
        int src = csr_src[s + i];
        float4 raw = *reinterpret_cast<const float4*>(hs + (size_t)src * HD + q * 8);
        const __half2* hp = reinterpret_cast<const __half2*>(&raw);
        #pragma unroll
        for (int j = 0; j < 4; j++) {
            float2 f2 = __half22float2(hp[j]);
            acc[2 * j]     += f2.x;
            acc[2 * j + 1] += f2.y;
        }
    }
    #pragma unroll
    for (int off = 4; off < 64; off <<= 1) {
        #pragma unroll
        for (int j = 0; j < 8; j++) acc[j] += __shfl_xor(acc[j], off);
    }
    if (es == 0) {
        float dv = dinv[wid];
        float4 w0, w1;
        w0.x = bias[q * 8 + 0] + dv * acc[0];
        w0.y = bias[q * 8 + 1] + dv * acc[1];
        w0.z = bias[q * 8 + 2] + dv * acc[2];
        w0.w = bias[q * 8 + 3] + dv * acc[3];
        w1.x = bias[q * 8 + 4] + dv * acc[4];
        w1.y = bias[q * 8 + 5] + dv * acc[5];
        w1.z = bias[q * 8 + 6] + dv * acc[6];
        w1.w = bias[q * 8 + 7] + dv * acc[7];
        float* op = outb + (size_t)wid * HD + q * 8;
        *reinterpret_cast<float4*>(op)     = w0;
        *reinterpret_cast<float4*>(op + 4) = w1;
    }
}

// Fused GraphNorm (stats + normalize) + optional residual + ReLU + optional mean-pool+linear.
// One block per graph (batch sorted => contiguous node range). y = A*x + B.
template <bool RES, bool POOL>
__global__ __launch_bounds__(256) void k_gnorm(const float* __restrict__ o,
                                               const int* __restrict__ gstart,
                                               const float* __restrict__ gamma,
                                               const float* __restrict__ beta,
                                               const float* __restrict__ msc,
                                               const float* __restrict__ xprev,
                                               float* __restrict__ xout,
                                               const float* __restrict__ Wl,
                                               const float* __restrict__ bl,
                                               float* __restrict__ outf) {
    int g = blockIdx.x;
    int s = gstart[g], e = gstart[g + 1];
    int f = threadIdx.x & 31, nl = threadIdx.x >> 5;   // 8 node-lanes x 32 features
    float as = 0.f, aq = 0.f;
    for (int v = s + nl; v < e; v += 8) {
        float xv = o[(size_t)v * HD + f];
        as += xv;
        aq += xv * xv;
    }
    __shared__ float ls[256], lq[256];
    __shared__ float sA[HD], sB[HD];
    ls[threadIdx.x] = as;
    lq[threadIdx.x] = aq;
    __syncthreads();
    if (threadIdx.x < HD) {
        float ss = 0.f, qq = 0.f;
        #pragma unroll
        for (int k = 0; k < 8; k++) { ss += ls[k * 32 + f]; qq += lq[k * 32 + f]; }
        float inv = 1.f / fmaxf((float)(e - s), 1.f);
        float m = ss * inv, mq = qq * inv, ms = msc[f];
        // var = E[(x - m*ms)^2] = E[x^2] - m^2 * ms * (2 - ms)
        float var = mq - m * m * ms * (2.f - ms);
        float A = gamma[f] * rsqrtf(var + EPSV);
        sA[f] = A;
        sB[f] = beta[f] - A * m * ms;
    }
    __syncthreads();
    float A = sA[f], B = sB[f];
    float pool = 0.f;
    for (int v = s + nl; v < e; v += 8) {
        float xv = o[(size_t)v * HD + f];
        float y = A * xv + B;
        if (RES) y += xprev[(size_t)v * HD + f];
        y = fmaxf(y, 0.f);
        xout[(size_t)v * HD + f] = y;
        if (POOL) pool += y;
    }
    if (POOL) {
        __syncthreads();
        ls[threadIdx.x] = pool;
        __syncthreads();
        if (threadIdx.x < HD) {
            float ss = 0.f;
            #pragma unroll
            for (int k = 0; k < 8; k++) ss += ls[k * 32 + f];
            lq[f] = ss / fmaxf((float)(e - s), 1.f);   // reuse lq: per-feature graph mean
        }
        __syncthreads();
        if (threadIdx.x < 3) {
            float acc = bl[threadIdx.x];
            #pragma unroll
            for (int f2 = 0; f2 < HD; f2++) acc += lq[f2] * Wl[f2 * 3 + threadIdx.x];
            outf[g * 3 + threadIdx.x] = acc;
        }
    }
}

extern "C" void kernel_launch(void* const* d_in, const int* in_sizes, int n_in,
                              void* d_out, int out_size, void* d_ws, size_t ws_size,
                              hipStream_t stream) {
    const float* x     = (const float*)d_in[0];
    const int*   ei    = (const int*)d_in[1];     // [2, NE]
    const int*   batch = (const int*)d_in[2];
    const float* W1 = (const float*)d_in[3];
    const float* b1 = (const float*)d_in[4];
    const float* W2 = (const float*)d_in[5];
    const float* b2 = (const float*)d_in[6];
    const float* W3 = (const float*)d_in[7];
    const float* b3 = (const float*)d_in[8];
    const float* g1 = (const float*)d_in[9];
    const float* be1 = (const float*)d_in[10];
    const float* ms1 = (const float*)d_in[11];
    const float* g2 = (const float*)d_in[12];
    const float* be2 = (const float*)d_in[13];
    const float* ms2 = (const float*)d_in[14];
    const float* g3 = (const float*)d_in[15];
    const float* be3 = (const float*)d_in[16];
    const float* ms3 = (const float*)d_in[17];
    const float* Wl = (const float*)d_in[18];
    const float* bl = (const float*)d_in[19];
    float* out = (float*)d_out;

    const int* row = ei;
    const int* col = ei + NE;

    // ---- workspace layout (16B aligned) ----
    char* ws = (char*)d_ws;
    size_t off = 0;
    // zeroed region:
    int*   fill    = (int*)(ws + off);   off += (size_t)NN * 4;
    int*   deg     = (int*)(ws + off);   off += (size_t)NN * 4;
    int*   counter = (int*)(ws + off);   off += 16;
    size_t zero_bytes = off;
    // non-zeroed region:
    int*   start   = (int*)(ws + off);   off += (size_t)NN * 4;
    float* dinv    = (float*)(ws + off); off += (size_t)NN * 4;
    int*   gstart  = (int*)(ws + off);   off += (size_t)(NG + 4) * 4;
    int*   csr_src = (int*)(ws + off);   off += (size_t)(NE + NN) * 4;
    __half* bufH   = (__half*)(ws + off); off += (size_t)NN * HD * 2;
    float* bufO    = (float*)(ws + off); off += (size_t)NN * HD * 4;
    float* bufX    = (float*)(ws + off); off += (size_t)NN * HD * 4;
    (void)ws_size; (void)in_sizes; (void)n_in; (void)out_size;

    hipMemsetAsync(ws, 0, zero_bytes, stream);

    const int nb_n   = (NN + 255) / 256;             // 391
    const int nb_e   = (NE + 255) / 256;             // 6250
    const int nb_no  = (NN * 4 + 255) / 256;         // 1563  (node-octet threads)
    const int nb_gw  = (NN * 64 + 255) / 256;        // 25000 (wave per node)

    // ---- CSR build (once, reused by all 3 convs) ----
    k_bound<<<nb_n, 256, 0, stream>>>(batch, gstart);
    k_count<<<nb_e, 256, 0, stream>>>(col, deg);
    k_alloc<<<nb_n, 256, 0, stream>>>(deg, start, dinv, counter);
    k_fill <<<FILL_BLOCKS, 256, 0, stream>>>(row, col, start, fill, csr_src);

    // ---- layer 1 ----
    k_premul<3><<<nb_no, 256, 0, stream>>>(x, W1, dinv, bufH);
    k_gather<<<nb_gw, 256, 0, stream>>>(bufH, csr_src, start, deg, dinv, b1, bufO);
    k_gnorm<false, false><<<NG, 256, 0, stream>>>(bufO, gstart, g1, be1, ms1,
                                                  nullptr, bufX, nullptr, nullptr, nullptr);

    // ---- layer 2 ----
    k_premul<HD><<<nb_no, 256, 0, stream>>>(bufX, W2, dinv, bufH);
    k_gather<<<nb_gw, 256, 0, stream>>>(bufH, csr_src, start, deg, dinv, b2, bufO);
    k_gnorm<true, false><<<NG, 256, 0, stream>>>(bufO, gstart, g2, be2, ms2,
                                                 bufX, bufX, nullptr, nullptr, nullptr);

    // ---- layer 3 (pool + linear fused) ----
    k_premul<HD><<<nb_no, 256, 0, stream>>>(bufX, W3, dinv, bufH);
    k_gather<<<nb_gw, 256, 0, stream>>>(bufH, csr_src, start, deg, dinv, b3, bufO);
    k_gnorm<true, true><<<NG, 256, 0, stream>>>(bufO, gstart, g3, be3, ms3,
                                                bufX, bufX, Wl, bl, out);
}